// Round 1
// baseline (505.668 us; speedup 1.0000x reference)
//
#include <hip/hip_runtime.h>
#include <math.h>

#define T_ 1024
#define BS_ 8
#define D_ 512
#define NROWS_ (BS_*2*T_)   // 16384
#define ALPHA_ 0.1f

// -------------------- Kernel A: Wh = h @ W  (f32 SIMT GEMM) --------------------
// grid = (16384/64) * (512/64) = 2048 blocks, 256 threads, 4x4 per thread
__global__ __launch_bounds__(256) void k_gemm_wh(
    const float* __restrict__ xa, const float* __restrict__ xv,
    const float* __restrict__ W, float* __restrict__ Wh)
{
    __shared__ float As[32][68];   // [k][m], padded
    __shared__ float Bs[32][68];   // [k][n], padded
    const int tid  = threadIdx.x;
    const int m0   = (blockIdx.x >> 3) << 6;
    const int n0   = (blockIdx.x & 7) << 6;
    const int tm   = (tid >> 4) << 2;
    const int tn   = (tid & 15) << 2;

    float acc[4][4] = {{0.f,0.f,0.f,0.f},{0.f,0.f,0.f,0.f},{0.f,0.f,0.f,0.f},{0.f,0.f,0.f,0.f}};

    for (int k0 = 0; k0 < D_; k0 += 32) {
        #pragma unroll
        for (int p = 0; p < 2; ++p) {
            int f4  = tid + p*256;          // 0..511
            int row = f4 >> 3;              // 0..63
            int k4  = (f4 & 7) << 2;        // 0..28
            int m   = m0 + row;
            int q   = m >> 10;              // 0..15 (b*2+blk)
            int i   = m & 1023;
            const float* src = ((q & 1) ? xv : xa)
                             + ((size_t)((q >> 1) * 1024 + i) * D_ + k0 + k4);
            float4 v = *(const float4*)src;
            As[k4+0][row] = v.x; As[k4+1][row] = v.y;
            As[k4+2][row] = v.z; As[k4+3][row] = v.w;
        }
        #pragma unroll
        for (int p = 0; p < 2; ++p) {
            int f4 = tid + p*256;
            int kr = f4 >> 4;               // 0..31
            int n4 = (f4 & 15) << 2;        // 0..60
            *(float4*)&Bs[kr][n4] = *(const float4*)(W + (size_t)(k0 + kr)*D_ + n0 + n4);
        }
        __syncthreads();
        #pragma unroll
        for (int k = 0; k < 32; ++k) {
            float4 a4 = *(const float4*)&As[k][tm];
            float4 b4 = *(const float4*)&Bs[k][tn];
            float av[4] = {a4.x, a4.y, a4.z, a4.w};
            float bv[4] = {b4.x, b4.y, b4.z, b4.w};
            #pragma unroll
            for (int ii = 0; ii < 4; ++ii)
                #pragma unroll
                for (int jj = 0; jj < 4; ++jj)
                    acc[ii][jj] = fmaf(av[ii], bv[jj], acc[ii][jj]);
        }
        __syncthreads();
    }
    #pragma unroll
    for (int ii = 0; ii < 4; ++ii) {
        float4 o = make_float4(acc[ii][0], acc[ii][1], acc[ii][2], acc[ii][3]);
        *(float4*)(Wh + (size_t)(m0 + tm + ii)*D_ + n0 + tn) = o;
    }
}

// -------------------- Kernel B: row stats Wh1, Wh2, sq --------------------
// one wave per row; grid = 16384/4 blocks of 256
__global__ __launch_bounds__(256) void k_rowstats(
    const float* __restrict__ Wh, const float* __restrict__ a,
    float* __restrict__ Wh1, float* __restrict__ Wh2, float* __restrict__ sq)
{
    __shared__ float sa[2*D_];
    const int tid = threadIdx.x;
    for (int i = tid; i < 2*D_; i += 256) sa[i] = a[i];
    __syncthreads();

    const int lane = tid & 63;
    const int row  = (blockIdx.x << 2) + (tid >> 6);
    const float* wr = Wh + (size_t)row * D_;

    float s1 = 0.f, s2 = 0.f, ss = 0.f;
    #pragma unroll
    for (int w = 0; w < 2; ++w) {
        int c = (lane + (w << 6)) << 2;     // 0..1020 step 4
        float4 v = *(const float4*)(wr + c);
        s1 = fmaf(v.x, sa[c+0], s1); s1 = fmaf(v.y, sa[c+1], s1);
        s1 = fmaf(v.z, sa[c+2], s1); s1 = fmaf(v.w, sa[c+3], s1);
        s2 = fmaf(v.x, sa[D_+c+0], s2); s2 = fmaf(v.y, sa[D_+c+1], s2);
        s2 = fmaf(v.z, sa[D_+c+2], s2); s2 = fmaf(v.w, sa[D_+c+3], s2);
        ss = fmaf(v.x, v.x, ss); ss = fmaf(v.y, v.y, ss);
        ss = fmaf(v.z, v.z, ss); ss = fmaf(v.w, v.w, ss);
    }
    #pragma unroll
    for (int off = 32; off > 0; off >>= 1) {
        s1 += __shfl_down(s1, off);
        s2 += __shfl_down(s2, off);
        ss += __shfl_down(ss, off);
    }
    if (lane == 0) { Wh1[row] = s1; Wh2[row] = s2; sq[row] = ss; }
}

// -------------------- Kernel C: per-block Gram + running top-4 --------------------
// grid = 16 (b,blk) * 32 row-tiles = 512 blocks of 256 threads
// each block: 32 rows x 1024 cols, K=512, col-tiles of 128
__global__ __launch_bounds__(256) void k_gram_topk(
    const float* __restrict__ Wh, const float* __restrict__ sq,
    int* __restrict__ topk)
{
    __shared__ float As[32][36];     // [k][row]
    __shared__ float Bs[32][132];    // [k][col]
    __shared__ float pdt[32][132];   // [row][col]
    __shared__ float sqc[128];

    const int tid     = threadIdx.x;
    const int p       = blockIdx.x >> 5;            // 0..15
    const int rt      = blockIdx.x & 31;            // 0..31
    const int rowbase = (p << 10) + (rt << 5);
    const int colbase = p << 10;

    const int r4 = (tid >> 5) << 2;   // 0..28
    const int c4 = (tid & 31) << 2;   // 0..124

    float sqr[4];
    #pragma unroll
    for (int ii = 0; ii < 4; ++ii) sqr[ii] = sq[rowbase + r4 + ii];

    float bv0 = -3.4e38f, bv1 = -3.4e38f, bv2 = -3.4e38f, bv3 = -3.4e38f;
    int   bi0 = 0, bi1 = 0, bi2 = 0, bi3 = 0;

    for (int ct = 0; ct < 8; ++ct) {
        const int cb = ct << 7;
        if (tid < 32)
            *(float4*)&sqc[tid << 2] = *(const float4*)(sq + colbase + cb + (tid << 2));

        float acc[4][4] = {{0.f,0.f,0.f,0.f},{0.f,0.f,0.f,0.f},{0.f,0.f,0.f,0.f},{0.f,0.f,0.f,0.f}};

        for (int k0 = 0; k0 < D_; k0 += 32) {
            {
                int row = tid >> 3;             // 0..31
                int k4  = (tid & 7) << 2;       // 0..28
                float4 v = *(const float4*)(Wh + (size_t)(rowbase + row)*D_ + k0 + k4);
                As[k4+0][row] = v.x; As[k4+1][row] = v.y;
                As[k4+2][row] = v.z; As[k4+3][row] = v.w;
            }
            #pragma unroll
            for (int pp = 0; pp < 4; ++pp) {
                int f4  = tid + pp*256;         // 0..1023
                int col = f4 >> 3;              // 0..127
                int k4  = (f4 & 7) << 2;
                float4 v = *(const float4*)(Wh + (size_t)(colbase + cb + col)*D_ + k0 + k4);
                Bs[k4+0][col] = v.x; Bs[k4+1][col] = v.y;
                Bs[k4+2][col] = v.z; Bs[k4+3][col] = v.w;
            }
            __syncthreads();
            #pragma unroll
            for (int k = 0; k < 32; ++k) {
                float4 a4 = *(const float4*)&As[k][r4];
                float4 b4 = *(const float4*)&Bs[k][c4];
                float av[4] = {a4.x, a4.y, a4.z, a4.w};
                float bw[4] = {b4.x, b4.y, b4.z, b4.w};
                #pragma unroll
                for (int ii = 0; ii < 4; ++ii)
                    #pragma unroll
                    for (int jj = 0; jj < 4; ++jj)
                        acc[ii][jj] = fmaf(av[ii], bw[jj], acc[ii][jj]);
            }
            __syncthreads();
        }
        // pd = -((sq_i - 2G) + sq_j)
        #pragma unroll
        for (int ii = 0; ii < 4; ++ii) {
            float4 o;
            o.x = -((sqr[ii] - 2.f*acc[ii][0]) + sqc[c4+0]);
            o.y = -((sqr[ii] - 2.f*acc[ii][1]) + sqc[c4+1]);
            o.z = -((sqr[ii] - 2.f*acc[ii][2]) + sqc[c4+2]);
            o.w = -((sqr[ii] - 2.f*acc[ii][3]) + sqc[c4+3]);
            *(float4*)&pdt[r4+ii][c4] = o;
        }
        __syncthreads();
        if (tid < 32) {
            for (int j = 0; j < 128; ++j) {
                float x = pdt[tid][j];
                int  id = cb + j;
                if (x > bv3) {                       // strict > keeps lowest index on ties
                    if (x > bv2) {
                        bv3 = bv2; bi3 = bi2;
                        if (x > bv1) {
                            bv2 = bv1; bi2 = bi1;
                            if (x > bv0) { bv1 = bv0; bi1 = bi0; bv0 = x; bi0 = id; }
                            else         { bv1 = x;  bi1 = id; }
                        } else { bv2 = x; bi2 = id; }
                    } else { bv3 = x; bi3 = id; }
                }
            }
        }
        __syncthreads();
    }
    if (tid < 32) {
        int* dst = topk + ((size_t)(rowbase + tid) << 2);
        dst[0] = bi0; dst[1] = bi1; dst[2] = bi2; dst[3] = bi3;
    }
}

// -------------------- Kernel D: sparse softmax + aggregate + elu --------------------
// one wave per row; grid = 16384/4 blocks of 256
__global__ __launch_bounds__(256) void k_aggregate(
    const float* __restrict__ Wh, const float* __restrict__ Wh1,
    const float* __restrict__ Wh2, const int* __restrict__ topk,
    float* __restrict__ out)
{
    const int tid  = threadIdx.x;
    const int lane = tid & 63;
    const int r    = (blockIdx.x << 2) + (tid >> 6);
    const int p    = r >> 10;       // 0..15 (b*2+blk)
    const int i    = r & 1023;
    const int rb   = p << 10;       // block base row

    const int  tM = i - 1, tC = i, tP = i + 1;
    const bool vM = (i > 0), vP = (i < T_ - 1);

    const int* tk = topk + ((size_t)r << 2);
    int s0 = tk[0], s1 = tk[1], s2 = tk[2], s3 = tk[3];

    bool u0 = !((vM && s0 == tM) || (s0 == tC) || (vP && s0 == tP));
    bool u1 = !((vM && s1 == tM) || (s1 == tC) || (vP && s1 == tP));
    bool u2 = !((vM && s2 == tM) || (s2 == tC) || (vP && s2 == tP));
    bool u3 = !((vM && s3 == tM) || (s3 == tC) || (vP && s3 == tP));

    int  ci[7] = { vM ? tM : 0, tC, vP ? tP : 0, s0, s1, s2, s3 };
    bool cv[7] = { vM, true, vP, u0, u1, u2, u3 };

    const float e1 = Wh1[r];
    float ev[7];
    float m = -3.4e38f;
    #pragma unroll
    for (int q = 0; q < 7; ++q) {
        float e = e1 + Wh2[rb + ci[q]];
        e = (e > 0.f) ? e : ALPHA_ * e;       // leaky relu
        e = cv[q] ? e : -3.4e38f;
        ev[q] = e;
        m = fmaxf(m, e);
    }
    float wsum = 0.f;
    #pragma unroll
    for (int q = 0; q < 7; ++q) {
        float w = cv[q] ? expf(ev[q] - m) : 0.f;
        ev[q] = w;
        wsum += w;
    }
    #pragma unroll
    for (int q = 0; q < 7; ++q) ev[q] /= wsum;

    const int c0 = lane << 2;                 // 0..252
    float4 A0 = {0.f,0.f,0.f,0.f}, A1 = {0.f,0.f,0.f,0.f};
    #pragma unroll
    for (int q = 0; q < 7; ++q) {
        if (ev[q] > 0.f) {
            const float wq = ev[q];
            const float* wrow = Wh + (size_t)(rb + ci[q]) * D_;
            float4 v0 = *(const float4*)(wrow + c0);
            float4 v1 = *(const float4*)(wrow + 256 + c0);
            A0.x = fmaf(wq, v0.x, A0.x); A0.y = fmaf(wq, v0.y, A0.y);
            A0.z = fmaf(wq, v0.z, A0.z); A0.w = fmaf(wq, v0.w, A0.w);
            A1.x = fmaf(wq, v1.x, A1.x); A1.y = fmaf(wq, v1.y, A1.y);
            A1.z = fmaf(wq, v1.z, A1.z); A1.w = fmaf(wq, v1.w, A1.w);
        }
    }
    // elu (alpha=1)
    A0.x = (A0.x > 0.f) ? A0.x : expm1f(A0.x);
    A0.y = (A0.y > 0.f) ? A0.y : expm1f(A0.y);
    A0.z = (A0.z > 0.f) ? A0.z : expm1f(A0.z);
    A0.w = (A0.w > 0.f) ? A0.w : expm1f(A0.w);
    A1.x = (A1.x > 0.f) ? A1.x : expm1f(A1.x);
    A1.y = (A1.y > 0.f) ? A1.y : expm1f(A1.y);
    A1.z = (A1.z > 0.f) ? A1.z : expm1f(A1.z);
    A1.w = (A1.w > 0.f) ? A1.w : expm1f(A1.w);

    const int blk = p & 1, b = p >> 1;
    float* dst = out + (size_t)blk * ((size_t)BS_ * T_ * D_)
               + ((size_t)((b << 10) + i)) * D_;
    *(float4*)(dst + c0)       = A0;
    *(float4*)(dst + 256 + c0) = A1;
}

extern "C" void kernel_launch(void* const* d_in, const int* in_sizes, int n_in,
                              void* d_out, int out_size, void* d_ws, size_t ws_size,
                              hipStream_t stream)
{
    const float* xa = (const float*)d_in[0];
    const float* xv = (const float*)d_in[1];
    const float* W  = (const float*)d_in[2];
    const float* a  = (const float*)d_in[3];
    float* out = (float*)d_out;

    float* Wh  = (float*)d_ws;                       // 16384*512 f32 = 33.55 MB
    float* Wh1 = Wh  + (size_t)NROWS_ * D_;
    float* Wh2 = Wh1 + NROWS_;
    float* sq  = Wh2 + NROWS_;
    int*  topk = (int*)(sq + NROWS_);                // 16384*4 ints

    k_gemm_wh  <<<dim3(2048), dim3(256), 0, stream>>>(xa, xv, W, Wh);
    k_rowstats <<<dim3(4096), dim3(256), 0, stream>>>(Wh, a, Wh1, Wh2, sq);
    k_gram_topk<<<dim3(512),  dim3(256), 0, stream>>>(Wh, sq, topk);
    k_aggregate<<<dim3(4096), dim3(256), 0, stream>>>(Wh, Wh1, Wh2, topk, out);
}